// Round 2
// baseline (235.031 us; speedup 1.0000x reference)
//
#include <hip/hip_runtime.h>
#include <math.h>

#define BATCH 16
#define CH 256
#define HW 56
#define NPIX (HW*HW)          // 3136
#define KK 7
#define NPOOL (KK*KK)         // 49
#define GG 4
#define RR 64

// ---------------- Kernel 1: fused dwconv-bn x2 + relu6 gate + pooled block means ----
// LDS halo stride 60 floats: b128 chunk -> bank-quad = (7*row + jq + k) mod 8 (uniform)
#define S1 60
__global__ __launch_bounds__(256) void k1_fuse(
    const float* __restrict__ x1,
    const float* __restrict__ dw1w, const float* __restrict__ g1, const float* __restrict__ b1,
    const float* __restrict__ m1, const float* __restrict__ v1,
    const float* __restrict__ dw2w, const float* __restrict__ g2, const float* __restrict__ b2,
    const float* __restrict__ m2, const float* __restrict__ v2,
    float* __restrict__ xf,      // d_out reused as x_fuse [B*C*3136]
    float* __restrict__ pooled)  // [B*C*49]
{
    const int bc = blockIdx.x;        // b*256 + c
    const int c  = bc & 255;
    const int t  = threadIdx.x;

    __shared__ __attribute__((aligned(16))) float halo[58*S1];  // 13.9 KB
    __shared__ float cells[49];

    {   // vectorized zero-init
        float4 z = make_float4(0.f, 0.f, 0.f, 0.f);
        float4* h4 = (float4*)halo;
        for (int i = t; i < 58*S1/4; i += 256) h4[i] = z;
        if (t < 49) cells[t] = 0.f;
    }
    __syncthreads();

    // stage: scalar global loads (coalesced), stride-1 LDS writes (conflict-free)
    const float* xp = x1 + (size_t)bc * NPIX;
    for (int idx = t; idx < NPIX; idx += 256) {
        float v = xp[idx];
        int i = idx / 56, j = idx - i * 56;
        halo[(i+1)*S1 + j + 1] = v;
    }

    float w1[9], w2[9];
    #pragma unroll
    for (int k = 0; k < 9; k++) { w1[k] = dw1w[c*9+k]; w2[k] = dw2w[c*9+k]; }
    const float sc1 = g1[c] * rsqrtf(v1[c] + 1e-5f);
    const float be1 = b1[c] - m1[c] * sc1;
    const float sc2 = g2[c] * rsqrtf(v2[c] + 1e-5f);
    const float be2 = b2[c] - m2[c] * sc2;
    __syncthreads();

    float4* op4 = (float4*)(xf + (size_t)bc * NPIX);
    for (int idx = t; idx < NPIX/4; idx += 256) {
        int i  = idx / 14;
        int j0 = (idx - i * 14) * 4;
        float rb[3][6];
        #pragma unroll
        for (int di = 0; di < 3; di++) {
            const float* hr = &halo[(i+di)*S1 + j0];   // 16B aligned (j0 % 4 == 0)
            float4 a = *(const float4*)hr;             // ds_read_b128
            float2 b = *(const float2*)(hr + 4);       // ds_read_b64
            rb[di][0]=a.x; rb[di][1]=a.y; rb[di][2]=a.z; rb[di][3]=a.w;
            rb[di][4]=b.x; rb[di][5]=b.y;
        }
        float res[4];
        #pragma unroll
        for (int e = 0; e < 4; e++) {
            float y1 = 0.f, y2 = 0.f;
            #pragma unroll
            for (int di = 0; di < 3; di++) {
                #pragma unroll
                for (int dj = 0; dj < 3; dj++) {
                    float xv = rb[di][e+dj];
                    y1 += xv * w1[di*3+dj];
                    y2 += xv * w2[di*3+dj];
                }
            }
            y1 = y1 * sc1 + be1;
            y2 = y2 * sc2 + be2;
            float a = fminf(fmaxf(y1, 0.f), 6.f);
            res[e] = a * y2;
        }
        float4 r4; r4.x = res[0]; r4.y = res[1]; r4.z = res[2]; r4.w = res[3];
        op4[idx] = r4;
        // each quad lies entirely in one 8x8 pool cell (j0 % 8 in {0,4})
        int ph = i >> 3, pw = j0 >> 3;
        atomicAdd(&cells[ph*7 + pw], res[0] + res[1] + res[2] + res[3]);
    }
    __syncthreads();
    if (t < 49) pooled[(size_t)bc * 49 + t] = cells[t] * (1.f/64.f);
}

// ---------------- Kernel 2a: h[b][p][o] = gelu(pw1 . pooled + pb1), p=49 is mean ----
__global__ __launch_bounds__(256) void k2a(
    const float* __restrict__ pooled, const float* __restrict__ pw1,
    const float* __restrict__ pb1, float* __restrict__ h)
{
    const int b  = blockIdx.x;
    const int oc = blockIdx.y;        // output chunk 0..3 (16 o each)
    const int t  = threadIdx.x;
    __shared__ float pl[256*50];      // 50 KB: [c][p], p=49 -> channel mean

    const float* pp = pooled + (size_t)b * 256 * 49;
    for (int idx = t; idx < 256*49; idx += 256) {
        int cc = idx / 49, p = idx - cc * 49;
        pl[cc*50 + p] = pp[idx];
    }
    __syncthreads();
    {   // per-channel mean (mean over 49 uniform block means == plane mean)
        float s = 0.f;
        #pragma unroll
        for (int p = 0; p < 49; p++) s += pl[t*50 + p];
        pl[t*50 + 49] = s * (1.f/49.f);
    }
    __syncthreads();

    for (int idx = t; idx < 16*50; idx += 256) {
        int ol = idx / 50, p = idx - ol * 50;
        int o = oc * 16 + ol;
        const float* wrow = pw1 + o * 256;
        float acc = pb1[o];
        #pragma unroll 8
        for (int cc = 0; cc < 256; cc++) acc += wrow[cc] * pl[cc*50 + p];
        float gv = 0.5f * acc * (1.f + erff(acc * 0.70710678118654752f));
        h[((size_t)b * 50 + p) * 64 + o] = gv;   // transposed layout [B][50][64]
    }
}

// ---------------- Kernel 2b: second proj + softmax over G + dynamic w/b ------------
__global__ __launch_bounds__(256) void k2b(
    const float* __restrict__ h, const float* __restrict__ pw2, const float* __restrict__ pb2,
    const float* __restrict__ weight1, const float* __restrict__ bias1,
    float* __restrict__ w_dyn, float* __restrict__ b_dyn)
{
    const int b   = blockIdx.x;
    const int cch = blockIdx.y;       // 0..15, 16 channels each
    const int t   = threadIdx.x;
    const int c_base = cch * 16;

    __shared__ __attribute__((aligned(16))) float hl[50*64];  // 12.8 KB [p][r]
    __shared__ float sl[64*51];       // 13.1 KB [row][p], row = g*16+cl

    const float* hp = h + (size_t)b * 50 * 64;
    for (int i = t; i < 800; i += 256) ((float4*)hl)[i] = ((const float4*)hp)[i];

    const int row = t & 63;           // fixed per thread
    const int pb  = t >> 6;           // 0..3
    const int g   = row >> 4, cl = row & 15;
    const int o2  = (g << 8) + c_base + cl;

    float wreg[64];
    {
        const float4* w4 = (const float4*)(pw2 + (size_t)o2 * 64);
        #pragma unroll
        for (int r4 = 0; r4 < 16; r4++) {
            float4 v = w4[r4];
            wreg[4*r4] = v.x; wreg[4*r4+1] = v.y; wreg[4*r4+2] = v.z; wreg[4*r4+3] = v.w;
        }
    }
    const float bias2 = pb2[o2];
    __syncthreads();

    for (int p = pb; p < 50; p += 4) {
        const float4* hv = (const float4*)&hl[p*64];
        float acc = bias2;
        #pragma unroll
        for (int r4 = 0; r4 < 16; r4++) {
            float4 v = hv[r4];      // broadcast across wave (same p)
            acc += wreg[4*r4]*v.x + wreg[4*r4+1]*v.y + wreg[4*r4+2]*v.z + wreg[4*r4+3]*v.w;
        }
        sl[row*51 + p] = acc;
    }
    __syncthreads();

    for (int idx = t; idx < 16*50; idx += 256) {
        int cl2 = idx / 50, p = idx - cl2 * 50;
        float s0 = sl[(cl2     )*51 + p];
        float s1 = sl[(16 + cl2)*51 + p];
        float s2 = sl[(32 + cl2)*51 + p];
        float s3 = sl[(48 + cl2)*51 + p];
        float mx = fmaxf(fmaxf(s0, s1), fmaxf(s2, s3));
        float e0 = expf(s0-mx), e1 = expf(s1-mx), e2 = expf(s2-mx), e3 = expf(s3-mx);
        float inv = 1.f / (e0+e1+e2+e3);
        e0 *= inv; e1 *= inv; e2 *= inv; e3 *= inv;
        int cc = c_base + cl2;
        if (p < 49) {
            float wv = e0*weight1[(0*256+cc)*49+p] + e1*weight1[(1*256+cc)*49+p]
                     + e2*weight1[(2*256+cc)*49+p] + e3*weight1[(3*256+cc)*49+p];
            w_dyn[((size_t)b*256 + cc)*49 + p] = wv;
        } else {
            b_dyn[b*256 + cc] = e0*bias1[cc] + e1*bias1[256+cc] + e2*bias1[512+cc] + e3*bias1[768+cc];
        }
    }
}

// ---------------- Kernel 3: per-sample dynamic 7x7 depthwise conv (in-place on d_out)
// LDS stride 68 floats: b128 chunk -> bank-quad = (4ty+iy+tx+k) mod 8 (uniform)
#define S3 68
__global__ __launch_bounds__(256) void k3_dyn(
    const float* __restrict__ w_dyn, const float* __restrict__ b_dyn,
    float* __restrict__ io)   // d_out: x_fuse in, result out (per-plane, safe)
{
    const int bc = blockIdx.x;
    const int t  = threadIdx.x;
    __shared__ __attribute__((aligned(16))) float halo[62*S3];  // 16.9 KB

    {
        float4 z = make_float4(0.f, 0.f, 0.f, 0.f);
        float4* h4 = (float4*)halo;
        for (int i = t; i < 62*S3/4; i += 256) h4[i] = z;
    }
    __syncthreads();

    float* plane = io + (size_t)bc * NPIX;
    // stage: scalar global loads (coalesced), stride-1 LDS writes (conflict-free)
    for (int idx = t; idx < NPIX; idx += 256) {
        float v = plane[idx];
        int i = idx / 56, j = idx - i * 56;
        halo[(i+3)*S3 + j + 3] = v;
    }

    float w[49];
    const float* wp = w_dyn + (size_t)bc * 49;   // block-uniform -> s_loads
    #pragma unroll
    for (int k = 0; k < 49; k++) w[k] = wp[k];
    const float bias = b_dyn[bc];
    __syncthreads();

    // 14x14 tiles of 4x4 outputs, threads 0..195
    if (t < 196) {
        int ty = t / 14, tx = t - ty * 14;
        int oy = ty * 4, ox = tx * 4;
        float acc[4][4];
        #pragma unroll
        for (int a = 0; a < 4; a++)
            #pragma unroll
            for (int bb = 0; bb < 4; bb++) acc[a][bb] = bias;

        #pragma unroll
        for (int iy = 0; iy < 10; iy++) {
            const float* hr = &halo[(oy+iy)*S3 + ox];  // 16B aligned
            float4 a = *(const float4*)hr;             // 3x ds_read_b128
            float4 b = *(const float4*)(hr + 4);
            float4 c = *(const float4*)(hr + 8);
            float row[12];
            row[0]=a.x; row[1]=a.y; row[2]=a.z; row[3]=a.w;
            row[4]=b.x; row[5]=b.y; row[6]=b.z; row[7]=b.w;
            row[8]=c.x; row[9]=c.y; row[10]=c.z; row[11]=c.w;
            #pragma unroll
            for (int tyy = 0; tyy < 4; tyy++) {
                const int ky = iy - tyy;
                if (ky >= 0 && ky < 7) {
                    #pragma unroll
                    for (int txx = 0; txx < 4; txx++)
                        #pragma unroll
                        for (int kx = 0; kx < 7; kx++)
                            acc[tyy][txx] += row[txx+kx] * w[ky*7+kx];
                }
            }
        }
        #pragma unroll
        for (int tyy = 0; tyy < 4; tyy++) {
            float4 r4; r4.x = acc[tyy][0]; r4.y = acc[tyy][1]; r4.z = acc[tyy][2]; r4.w = acc[tyy][3];
            *(float4*)(plane + (oy+tyy)*56 + ox) = r4;
        }
    }
}

extern "C" void kernel_launch(void* const* d_in, const int* in_sizes, int n_in,
                              void* d_out, int out_size, void* d_ws, size_t ws_size,
                              hipStream_t stream) {
    const float* x1    = (const float*)d_in[0];
    const float* dw1w  = (const float*)d_in[1];
    const float* dw1g  = (const float*)d_in[2];
    const float* dw1b  = (const float*)d_in[3];
    const float* dw1m  = (const float*)d_in[4];
    const float* dw1v  = (const float*)d_in[5];
    const float* dw2w  = (const float*)d_in[6];
    const float* dw2g  = (const float*)d_in[7];
    const float* dw2b  = (const float*)d_in[8];
    const float* dw2m  = (const float*)d_in[9];
    const float* dw2v  = (const float*)d_in[10];
    const float* weight1 = (const float*)d_in[11];
    const float* bias1   = (const float*)d_in[12];
    const float* pw1     = (const float*)d_in[13];
    const float* pb1     = (const float*)d_in[14];
    const float* pw2     = (const float*)d_in[15];
    const float* pb2     = (const float*)d_in[16];

    float* out = (float*)d_out;
    float* ws  = (float*)d_ws;
    float* pooled = ws;                    // 16*256*49 = 200704
    float* h      = ws + 200704;           // 16*50*64  =  51200
    float* w_dyn  = ws + 251904;           // 16*256*49 = 200704
    float* b_dyn  = ws + 452608;           // 16*256    =   4096

    k1_fuse<<<BATCH*CH, 256, 0, stream>>>(x1, dw1w, dw1g, dw1b, dw1m, dw1v,
                                          dw2w, dw2g, dw2b, dw2m, dw2v, out, pooled);
    k2a<<<dim3(BATCH, 4), 256, 0, stream>>>(pooled, pw1, pb1, h);
    k2b<<<dim3(BATCH, 16), 256, 0, stream>>>(h, pw2, pb2, weight1, bias1, w_dyn, b_dyn);
    k3_dyn<<<BATCH*CH, 256, 0, stream>>>(w_dyn, b_dyn, out);
}

// Round 3
// 203.639 us; speedup vs baseline: 1.1542x; 1.1542x over previous
//
#include <hip/hip_runtime.h>
#include <math.h>

#define BATCH 16
#define CH 256
#define HW 56
#define NPIX (HW*HW)          // 3136
#define KK 7

// ---------------- Kernel 1: fused dwconv-bn x2 + relu6 gate + pooled block means ----
// halo layout: row stride 64 floats, left pad 4 (image col j -> LDS col j+4),
// top pad 1 (image row i -> LDS row i+1). All b128 accesses 16B-aligned.
#define S1 64
__global__ __launch_bounds__(256) void k1_fuse(
    const float* __restrict__ x1,
    const float* __restrict__ dw1w, const float* __restrict__ g1, const float* __restrict__ b1,
    const float* __restrict__ m1, const float* __restrict__ v1,
    const float* __restrict__ dw2w, const float* __restrict__ g2, const float* __restrict__ b2,
    const float* __restrict__ m2, const float* __restrict__ v2,
    float* __restrict__ xf,      // d_out reused as x_fuse [B*C*3136]
    float* __restrict__ pooled)  // [B*C*49]
{
    const int bc = blockIdx.x;        // b*256 + c
    const int c  = bc & 255;
    const int t  = threadIdx.x;

    __shared__ __attribute__((aligned(16))) float halo[58*S1];  // 14.8 KB
    __shared__ float part[196];

    {   // vectorized zero-init (borders must be 0; interior overwritten)
        float4 z = make_float4(0.f, 0.f, 0.f, 0.f);
        float4* h4 = (float4*)halo;
        for (int i = t; i < 58*S1/4; i += 256) h4[i] = z;
    }

    // uniform per-channel constants (scalar path, overlaps with memset)
    float w1[9], w2[9];
    #pragma unroll
    for (int k = 0; k < 9; k++) { w1[k] = dw1w[c*9+k]; w2[k] = dw2w[c*9+k]; }
    const float sc1 = g1[c] * rsqrtf(v1[c] + 1e-5f);
    const float be1 = b1[c] - m1[c] * sc1;
    const float sc2 = g2[c] * rsqrtf(v2[c] + 1e-5f);
    const float be2 = b2[c] - m2[c] * sc2;
    __syncthreads();

    // stage: 196 threads x 4 independent float4 loads (batched, one vmcnt wait),
    // then 4 aligned ds_write_b128 (stride-1 chunks -> conflict-free)
    const float4* xp4 = (const float4*)(x1 + (size_t)bc * NPIX);
    if (t < 196) {
        float4 v[4];
        #pragma unroll
        for (int q = 0; q < 4; q++) v[q] = xp4[q*196 + t];
        #pragma unroll
        for (int q = 0; q < 4; q++) {
            int p = (q*196 + t) * 4;
            int i = p / 56, j = p - i * 56;          // j % 4 == 0
            *(float4*)&halo[(i+1)*S1 + 4 + j] = v[q];
        }
    }
    __syncthreads();

    float tile_sum = 0.f;
    if (t < 196) {
        const int ty = t / 14, tx = t - ty * 14;     // 4x4 output tile at (4ty, 4tx)
        float y1a[4][4], y2a[4][4];
        #pragma unroll
        for (int a = 0; a < 4; a++)
            #pragma unroll
            for (int e = 0; e < 4; e++) { y1a[a][e] = 0.f; y2a[a][e] = 0.f; }

        #pragma unroll
        for (int iy = 0; iy < 6; iy++) {             // LDS rows 4ty .. 4ty+5
            const float* hr = &halo[(4*ty + iy)*S1 + 4*tx];
            float4 a4 = *(const float4*)hr;          // aligned b128
            float4 b4 = *(const float4*)(hr + 4);    // aligned b128
            float  c1 = hr[8];                       // b32
            float rb[9];
            rb[0]=a4.x; rb[1]=a4.y; rb[2]=a4.z; rb[3]=a4.w;
            rb[4]=b4.x; rb[5]=b4.y; rb[6]=b4.z; rb[7]=b4.w; rb[8]=c1;
            #pragma unroll
            for (int tyy = 0; tyy < 4; tyy++) {
                const int ky = iy - tyy;             // needs 0..2
                if (ky >= 0 && ky < 3) {
                    #pragma unroll
                    for (int e = 0; e < 4; e++)
                        #pragma unroll
                        for (int dj = 0; dj < 3; dj++) {
                            float xv = rb[3 + e + dj];   // image col 4tx+e+dj-1
                            y1a[tyy][e] += xv * w1[ky*3+dj];
                            y2a[tyy][e] += xv * w2[ky*3+dj];
                        }
                }
            }
        }
        float* plane = xf + (size_t)bc * NPIX;
        #pragma unroll
        for (int tyy = 0; tyy < 4; tyy++) {
            float res[4];
            #pragma unroll
            for (int e = 0; e < 4; e++) {
                float y1 = y1a[tyy][e] * sc1 + be1;
                float y2 = y2a[tyy][e] * sc2 + be2;
                float a = fminf(fmaxf(y1, 0.f), 6.f);
                res[e] = a * y2;
                tile_sum += res[e];
            }
            float4 r4; r4.x=res[0]; r4.y=res[1]; r4.z=res[2]; r4.w=res[3];
            *(float4*)(plane + (4*ty + tyy)*56 + 4*tx) = r4;
        }
        part[t] = tile_sum;   // tile (ty,tx) lies wholly in pool cell (ty>>1, tx>>1)
    }
    __syncthreads();
    if (t < 49) {
        int ph = t / 7, pw = t - ph * 7;
        float s = part[(2*ph  )*14 + 2*pw] + part[(2*ph  )*14 + 2*pw + 1]
                + part[(2*ph+1)*14 + 2*pw] + part[(2*ph+1)*14 + 2*pw + 1];
        pooled[(size_t)bc * 49 + t] = s * (1.f/64.f);
    }
}

// ---------------- Kernel 2a: h[b][p][o] = gelu(pw1 . pooled + pb1), p=49 is mean ----
__global__ __launch_bounds__(256) void k2a(
    const float* __restrict__ pooled, const float* __restrict__ pw1,
    const float* __restrict__ pb1, float* __restrict__ h)
{
    const int b  = blockIdx.x;
    const int oc = blockIdx.y;        // output chunk 0..3 (16 o each)
    const int t  = threadIdx.x;
    __shared__ float pl[256*50];      // 50 KB: [c][p], p=49 -> channel mean

    const float* pp = pooled + (size_t)b * 256 * 49;
    for (int idx = t; idx < 256*49; idx += 256) {
        int cc = idx / 49, p = idx - cc * 49;
        pl[cc*50 + p] = pp[idx];
    }
    __syncthreads();
    {   // per-channel mean (mean over 49 uniform block means == plane mean)
        float s = 0.f;
        #pragma unroll
        for (int p = 0; p < 49; p++) s += pl[t*50 + p];
        pl[t*50 + 49] = s * (1.f/49.f);
    }
    __syncthreads();

    for (int idx = t; idx < 16*50; idx += 256) {
        int ol = idx / 50, p = idx - ol * 50;
        int o = oc * 16 + ol;
        const float* wrow = pw1 + o * 256;
        float acc = pb1[o];
        #pragma unroll 8
        for (int cc = 0; cc < 256; cc++) acc += wrow[cc] * pl[cc*50 + p];
        float gv = 0.5f * acc * (1.f + erff(acc * 0.70710678118654752f));
        h[((size_t)b * 50 + p) * 64 + o] = gv;   // transposed layout [B][50][64]
    }
}

// ---------------- Kernel 2b: second proj + softmax over G + dynamic w/b ------------
__global__ __launch_bounds__(256) void k2b(
    const float* __restrict__ h, const float* __restrict__ pw2, const float* __restrict__ pb2,
    const float* __restrict__ weight1, const float* __restrict__ bias1,
    float* __restrict__ w_dyn, float* __restrict__ b_dyn)
{
    const int b   = blockIdx.x;
    const int cch = blockIdx.y;       // 0..15, 16 channels each
    const int t   = threadIdx.x;
    const int c_base = cch * 16;

    __shared__ __attribute__((aligned(16))) float hl[50*64];  // 12.8 KB [p][r]
    __shared__ float sl[64*51];       // 13.1 KB [row][p], row = g*16+cl

    const float* hp = h + (size_t)b * 50 * 64;
    for (int i = t; i < 800; i += 256) ((float4*)hl)[i] = ((const float4*)hp)[i];

    const int row = t & 63;           // fixed per thread
    const int pb  = t >> 6;           // 0..3
    const int g   = row >> 4, cl = row & 15;
    const int o2  = (g << 8) + c_base + cl;

    float wreg[64];
    {
        const float4* w4 = (const float4*)(pw2 + (size_t)o2 * 64);
        #pragma unroll
        for (int r4 = 0; r4 < 16; r4++) {
            float4 v = w4[r4];
            wreg[4*r4] = v.x; wreg[4*r4+1] = v.y; wreg[4*r4+2] = v.z; wreg[4*r4+3] = v.w;
        }
    }
    const float bias2 = pb2[o2];
    __syncthreads();

    for (int p = pb; p < 50; p += 4) {
        const float4* hv = (const float4*)&hl[p*64];
        float acc = bias2;
        #pragma unroll
        for (int r4 = 0; r4 < 16; r4++) {
            float4 v = hv[r4];      // broadcast across wave (same p)
            acc += wreg[4*r4]*v.x + wreg[4*r4+1]*v.y + wreg[4*r4+2]*v.z + wreg[4*r4+3]*v.w;
        }
        sl[row*51 + p] = acc;
    }
    __syncthreads();

    for (int idx = t; idx < 16*50; idx += 256) {
        int cl2 = idx / 50, p = idx - cl2 * 50;
        float s0 = sl[(cl2     )*51 + p];
        float s1 = sl[(16 + cl2)*51 + p];
        float s2 = sl[(32 + cl2)*51 + p];
        float s3 = sl[(48 + cl2)*51 + p];
        float mx = fmaxf(fmaxf(s0, s1), fmaxf(s2, s3));
        float e0 = expf(s0-mx), e1 = expf(s1-mx), e2 = expf(s2-mx), e3 = expf(s3-mx);
        float inv = 1.f / (e0+e1+e2+e3);
        e0 *= inv; e1 *= inv; e2 *= inv; e3 *= inv;
        int cc = c_base + cl2;
        if (p < 49) {
            float wv = e0*weight1[(0*256+cc)*49+p] + e1*weight1[(1*256+cc)*49+p]
                     + e2*weight1[(2*256+cc)*49+p] + e3*weight1[(3*256+cc)*49+p];
            w_dyn[((size_t)b*256 + cc)*49 + p] = wv;
        } else {
            b_dyn[b*256 + cc] = e0*bias1[cc] + e1*bias1[256+cc] + e2*bias1[512+cc] + e3*bias1[768+cc];
        }
    }
}

// ---------------- Kernel 3: per-sample dynamic 7x7 depthwise conv (in-place on d_out)
// halo layout: row stride 68 floats, left pad 4 (col j -> LDS col j+4),
// top pad 3 (row i -> LDS row i+3). All b128 accesses aligned.
#define S3 68
__global__ __launch_bounds__(256) void k3_dyn(
    const float* __restrict__ w_dyn, const float* __restrict__ b_dyn,
    float* __restrict__ io)   // d_out: x_fuse in, result out (per-plane, safe)
{
    const int bc = blockIdx.x;
    const int t  = threadIdx.x;
    __shared__ __attribute__((aligned(16))) float halo[62*S3];  // 16.9 KB

    {
        float4 z = make_float4(0.f, 0.f, 0.f, 0.f);
        float4* h4 = (float4*)halo;
        for (int i = t; i < 62*S3/4; i += 256) h4[i] = z;
    }

    float w[49];
    const float* wp = w_dyn + (size_t)bc * 49;   // block-uniform -> s_loads
    #pragma unroll
    for (int k = 0; k < 49; k++) w[k] = wp[k];
    const float bias = b_dyn[bc];
    __syncthreads();

    float* plane = io + (size_t)bc * NPIX;
    const float4* pl4 = (const float4*)plane;
    if (t < 196) {
        float4 v[4];
        #pragma unroll
        for (int q = 0; q < 4; q++) v[q] = pl4[q*196 + t];
        #pragma unroll
        for (int q = 0; q < 4; q++) {
            int p = (q*196 + t) * 4;
            int i = p / 56, j = p - i * 56;
            *(float4*)&halo[(i+3)*S3 + 4 + j] = v[q];
        }
    }
    __syncthreads();

    if (t < 196) {
        const int ty = t / 14, tx = t - ty * 14;
        const int oy = ty * 4, ox = tx * 4;
        float acc[4][4];
        #pragma unroll
        for (int a = 0; a < 4; a++)
            #pragma unroll
            for (int bb = 0; bb < 4; bb++) acc[a][bb] = bias;

        #pragma unroll
        for (int iy = 0; iy < 10; iy++) {
            const float* hr = &halo[(oy+iy)*S3 + ox];  // aligned
            float4 a = *(const float4*)hr;             // 3x ds_read_b128
            float4 b = *(const float4*)(hr + 4);
            float4 c = *(const float4*)(hr + 8);
            float row[12];                             // row[m] = image col ox+m-4
            row[0]=a.x; row[1]=a.y; row[2]=a.z; row[3]=a.w;
            row[4]=b.x; row[5]=b.y; row[6]=b.z; row[7]=b.w;
            row[8]=c.x; row[9]=c.y; row[10]=c.z; row[11]=c.w;
            #pragma unroll
            for (int tyy = 0; tyy < 4; tyy++) {
                const int ky = iy - tyy;
                if (ky >= 0 && ky < 7) {
                    #pragma unroll
                    for (int txx = 0; txx < 4; txx++)
                        #pragma unroll
                        for (int kx = 0; kx < 7; kx++)
                            acc[tyy][txx] += row[1+txx+kx] * w[ky*7+kx];
                }
            }
        }
        #pragma unroll
        for (int tyy = 0; tyy < 4; tyy++) {
            float4 r4; r4.x = acc[tyy][0]; r4.y = acc[tyy][1]; r4.z = acc[tyy][2]; r4.w = acc[tyy][3];
            *(float4*)(plane + (oy+tyy)*56 + ox) = r4;
        }
    }
}

extern "C" void kernel_launch(void* const* d_in, const int* in_sizes, int n_in,
                              void* d_out, int out_size, void* d_ws, size_t ws_size,
                              hipStream_t stream) {
    const float* x1    = (const float*)d_in[0];
    const float* dw1w  = (const float*)d_in[1];
    const float* dw1g  = (const float*)d_in[2];
    const float* dw1b  = (const float*)d_in[3];
    const float* dw1m  = (const float*)d_in[4];
    const float* dw1v  = (const float*)d_in[5];
    const float* dw2w  = (const float*)d_in[6];
    const float* dw2g  = (const float*)d_in[7];
    const float* dw2b  = (const float*)d_in[8];
    const float* dw2m  = (const float*)d_in[9];
    const float* dw2v  = (const float*)d_in[10];
    const float* weight1 = (const float*)d_in[11];
    const float* bias1   = (const float*)d_in[12];
    const float* pw1     = (const float*)d_in[13];
    const float* pb1     = (const float*)d_in[14];
    const float* pw2     = (const float*)d_in[15];
    const float* pb2     = (const float*)d_in[16];

    float* out = (float*)d_out;
    float* ws  = (float*)d_ws;
    float* pooled = ws;                    // 16*256*49 = 200704
    float* h      = ws + 200704;           // 16*50*64  =  51200
    float* w_dyn  = ws + 251904;           // 16*256*49 = 200704
    float* b_dyn  = ws + 452608;           // 16*256    =   4096

    k1_fuse<<<BATCH*CH, 256, 0, stream>>>(x1, dw1w, dw1g, dw1b, dw1m, dw1v,
                                          dw2w, dw2g, dw2b, dw2m, dw2v, out, pooled);
    k2a<<<dim3(BATCH, 4), 256, 0, stream>>>(pooled, pw1, pb1, h);
    k2b<<<dim3(BATCH, 16), 256, 0, stream>>>(h, pw2, pb2, weight1, bias1, w_dyn, b_dyn);
    k3_dyn<<<BATCH*CH, 256, 0, stream>>>(w_dyn, b_dyn, out);
}